// Round 6
// baseline (306.453 us; speedup 1.0000x reference)
//
#include <hip/hip_runtime.h>
#include <math.h>

#define B_N    32768
#define D_N    128
#define HIST_N 30
#define M_N    15
#define H_N    4

#define TILE_ROWS   128
#define TILE_FLOATS (TILE_ROWS * HIST_N)          // 3840 floats
#define TILE_BYTES  (TILE_FLOATS * 4)             // 15360 B
#define WAVE_ROWS   (TILE_ROWS / 4)               // 32 rows per wave
#define WAVE_FLOATS (TILE_FLOATS / 4)             // 960 floats = 3840 B
#define WAVE_BYTES  (WAVE_FLOATS * 4)
#define NBLOCKS     1024                          // 4 resident blocks per CU
#define TPB         (B_N * D_N / TILE_ROWS / NBLOCKS)  // 32 tiles per block
// per-wave DMA calls per tile: 3 x 16B-lane (3072B) + 3 x 4B-lane (768B) = 6
#define LOADS_PER_TILE 6

__device__ __forceinline__ void gload16(const void* g, float* l) {
    __builtin_amdgcn_global_load_lds(
        (const __attribute__((address_space(1))) unsigned int*)g,
        (__attribute__((address_space(3))) unsigned int*)l, 16, 0, 0);
}
__device__ __forceinline__ void gload4(const void* g, float* l) {
    __builtin_amdgcn_global_load_lds(
        (const __attribute__((address_space(1))) unsigned int*)g,
        (__attribute__((address_space(3))) unsigned int*)l, 4, 0, 0);
}

// ---------------------------------------------------------------------------
// Single fused persistent kernel (see r5 comments for the param-math identity).
// r6 change: 128-row tiles -> 33 KB LDS/block -> 4 blocks/CU -> 16 waves/CU.
// Per wave per tile: stage 32 rows (3840 B, 6 DMA loads), lanes<32 compute
// one row each. Wave-private counted-vmcnt pipeline, no main-loop barriers.
// ---------------------------------------------------------------------------
__global__ __launch_bounds__(256, 4) void fused_kernel(
        const float* __restrict__ pa,
        const float* __restrict__ w1,
        const float* __restrict__ b1,
        const float* __restrict__ b2,
        const float* __restrict__ b3,
        const float* __restrict__ cw,
        const float* __restrict__ ss,
        const float* __restrict__ sh,
        const float* __restrict__ al,
        const float* __restrict__ rs,
        float* __restrict__ out) {
    const int tid   = threadIdx.x;
    const int lane  = tid & 63;
    const int wv_id = tid >> 6;                 // wave 0..3
    const int d     = wv_id * WAVE_ROWS + (lane & (WAVE_ROWS - 1)); // 0..127

    __shared__ __align__(16) float lds[2][TILE_FLOATS];   // 30720 B
    __shared__ float W1c[H_N][D_N];                       // 2048 B
    __shared__ float Gsh[16];
    __shared__ float Msh[32];                             // M2[16], M3[16]

    const char* pab = (const char*)pa;
    const size_t tile0 = (size_t)blockIdx.x * TPB;

    auto issue_tile = [&](size_t t, int buf) {
        const char* gw = pab + t * TILE_BYTES + (size_t)wv_id * WAVE_BYTES;
        float* lw = &lds[buf][0] + wv_id * WAVE_FLOATS;
#pragma unroll
        for (int c = 0; c < 3; ++c)
            gload16(gw + c * 1024 + lane * 16, lw + c * 256);
#pragma unroll
        for (int c = 0; c < 3; ++c)
            gload4(gw + 3072 + c * 256 + lane * 4, lw + 768 + c * 64);
    };

    // prologue: two tiles in flight before anything else
    issue_tile(tile0, 0);
    issue_tile(tile0 + 1, 1);

    // ---- per-d parameter loads (regular VMEM, overlap the DMAs) ----
    float wv[M_N][H_N];
#pragma unroll
    for (int m = 0; m < M_N; ++m)
#pragma unroll
        for (int h = 0; h < H_N; ++h)
            wv[m][h] = w1[(m * H_N + h) * D_N + d];

    float b1v[H_N], b2v[H_N];
#pragma unroll
    for (int h = 0; h < H_N; ++h) {
        b1v[h] = b1[h * D_N + d];
        b2v[h] = b2[h * D_N + d];
    }
    const float b3v = b3[d];

    // ---- softmax(cw), redundant per-thread ----
    float swm[M_N];
    {
        float mx = cw[0];
#pragma unroll
        for (int m = 1; m < M_N; ++m) mx = fmaxf(mx, cw[m]);
        float s = 0.f;
#pragma unroll
        for (int m = 0; m < M_N; ++m) { swm[m] = expf(cw[m] - mx); s += swm[m]; }
        float inv = 1.f / s;
#pragma unroll
        for (int m = 0; m < M_N; ++m) swm[m] *= inv;
    }

    // ---- W1c into LDS (threads 0..127 own d=tid; needs w1 cols of tid) ----
    if (tid < 128) {
#pragma unroll
        for (int h = 0; h < H_N; ++h) {
            float acc = 0.f;
#pragma unroll
            for (int m = 0; m < M_N; ++m)
                acc = fmaf(swm[m], w1[(m * H_N + h) * D_N + tid], acc);
            W1c[h][tid] = acc;
        }
    }
    asm volatile("s_waitcnt lgkmcnt(0)" ::: "memory");
    __builtin_amdgcn_s_barrier();

    // ---- Gram (16 threads, staggered to avoid bank conflicts) ----
    if (tid < 16) {
        const int i = tid >> 2, j = tid & 3;
        float s = 0.f;
        for (int st = 0; st < 128; ++st) {
            int dd = (st + tid * 8) & 127;
            s = fmaf(W1c[i][dd], W1c[j][dd], s);
        }
        Gsh[tid] = s;
    }
    asm volatile("s_waitcnt lgkmcnt(0)" ::: "memory");
    __builtin_amdgcn_s_barrier();

    // ---- thread 0: Jacobi + two-stage spectral scalars -> M2, M3 ----
    if (tid == 0) {
        float G[4][4], U[4][4];
#pragma unroll
        for (int i = 0; i < 4; ++i)
#pragma unroll
            for (int j = 0; j < 4; ++j) {
                G[i][j] = Gsh[i * 4 + j];
                U[i][j] = (i == j) ? 1.f : 0.f;
            }
        for (int sweep = 0; sweep < 6; ++sweep)
            for (int p = 0; p < 3; ++p)
                for (int q = p + 1; q < 4; ++q) {
                    float apq = G[p][q];
                    if (fabsf(apq) < 1e-30f) continue;
                    float theta = (G[q][q] - G[p][p]) / (2.f * apq);
                    float t = ((theta >= 0.f) ? 1.f : -1.f) /
                              (fabsf(theta) + sqrtf(theta * theta + 1.f));
                    float c = 1.f / sqrtf(t * t + 1.f), sn = t * c;
                    for (int i = 0; i < 4; ++i) {
                        float gip = G[i][p], giq = G[i][q];
                        G[i][p] = c * gip - sn * giq;
                        G[i][q] = sn * gip + c * giq;
                    }
                    for (int i = 0; i < 4; ++i) {
                        float gpi = G[p][i], gqi = G[q][i];
                        G[p][i] = c * gpi - sn * gqi;
                        G[q][i] = sn * gpi + c * gqi;
                    }
                    for (int i = 0; i < 4; ++i) {
                        float uip = U[i][p], uiq = U[i][q];
                        U[i][p] = c * uip - sn * uiq;
                        U[i][q] = sn * uip + c * uiq;
                    }
                }
        float lam[4];
#pragma unroll
        for (int i = 0; i < 4; ++i) lam[i] = G[i][i];
        int ord[4] = {0, 1, 2, 3};
        for (int i = 0; i < 4; ++i)
            for (int j = i + 1; j < 4; ++j)
                if (lam[ord[j]] > lam[ord[i]]) { int t2 = ord[i]; ord[i] = ord[j]; ord[j] = t2; }

        const float a = al[0], r = rs[0];
        float c1[4], S2a[4];
        for (int p = 0; p < 4; ++p) {
            int e = ord[p];
            float S = sqrtf(fmaxf(lam[e], 0.f));
            float x = ss[p];
            float sp = (x > 20.f) ? x : log1pf(expf(x));
            float ratio = (S > 1e-30f) ? ((sp * S + sh[p]) / S) : sp;
            c1[e] = a * ratio + r;
            S2a[e] = fabsf(c1[e]) * S;      // |singular values| of W2
        }
        int ord2[4] = {0, 1, 2, 3};
        for (int i = 0; i < 4; ++i)
            for (int j = i + 1; j < 4; ++j)
                if (S2a[ord2[j]] > S2a[ord2[i]]) { int t2 = ord2[i]; ord2[i] = ord2[j]; ord2[j] = t2; }
        float c12[4];
        for (int p = 0; p < 4; ++p) {
            int e = ord2[p];
            float Sa = S2a[e];
            float x = ss[p];
            float sp = (x > 20.f) ? x : log1pf(expf(x));
            float ratio2 = (Sa > 1e-30f) ? ((sp * Sa + sh[p]) / Sa) : sp;
            c12[e] = (a * ratio2 + r) * c1[e];
        }
#pragma unroll
        for (int i = 0; i < 4; ++i)
#pragma unroll
            for (int j = 0; j < 4; ++j) {
                float m2 = 0.f, m3 = 0.f;
#pragma unroll
                for (int e = 0; e < 4; ++e) {
                    float uu = U[i][e] * U[j][e];
                    m2 = fmaf(uu, c1[e], m2);
                    m3 = fmaf(uu, c12[e], m3);
                }
                Msh[i * 4 + j] = m2;
                Msh[16 + i * 4 + j] = m3;
            }
    }
    asm volatile("s_waitcnt lgkmcnt(0)" ::: "memory");
    __builtin_amdgcn_s_barrier();

    // ---- per-thread W2/W3 columns ----
    float w2v[H_N], w3v[H_N];
#pragma unroll
    for (int h = 0; h < H_N; ++h) {
        float s2 = 0.f, s3 = 0.f;
#pragma unroll
        for (int k4 = 0; k4 < 4; ++k4) {
            float wc = W1c[k4][d];
            s2 = fmaf(Msh[h * 4 + k4], wc, s2);
            s3 = fmaf(Msh[16 + h * 4 + k4], wc, s3);
        }
        w2v[h] = s2;
        w3v[h] = s3;
    }

    const int row_in_wave = lane;               // lanes 0..31 compute
    const bool active = (lane < WAVE_ROWS);

    // ---- main streaming loop: per-wave counted-vmcnt pipeline ----
    for (int k = 0; k < TPB; ++k) {
        if (k == TPB - 1)
            asm volatile("s_waitcnt vmcnt(0)" ::: "memory");
        else
            asm volatile("s_waitcnt vmcnt(6)" ::: "memory");   // = LOADS_PER_TILE

        const float* L = &lds[k & 1][0] + (wv_id * WAVE_ROWS + row_in_wave) * HIST_N
                         + (HIST_N - M_N);
        if (active) {
            float x0 = L[0];
            float h1[H_N];
#pragma unroll
            for (int h = 0; h < H_N; ++h) h1[h] = x0 * wv[0][h];
#pragma unroll
            for (int c = 0; c < 7; ++c) {
                float2 q = *(const float2*)(L + 1 + 2 * c);   // 8B-aligned
#pragma unroll
                for (int h = 0; h < H_N; ++h) h1[h] = fmaf(q.x, wv[1 + 2 * c][h], h1[h]);
#pragma unroll
                for (int h = 0; h < H_N; ++h) h1[h] = fmaf(q.y, wv[2 + 2 * c][h], h1[h]);
            }
            float acc = b3v;
#pragma unroll
            for (int h = 0; h < H_N; ++h) {
                float v = fmaxf(h1[h] + b1v[h], 0.f);
                float u = fmaxf(fmaf(v, w2v[h], b2v[h]), 0.f);
                acc = fmaf(u, w3v[h], acc);
            }
            out[(tile0 + k) * TILE_ROWS + wv_id * WAVE_ROWS + row_in_wave] = acc;
        }

        asm volatile("" ::: "memory");   // pin reads/store before next DMA issue
        if (k + 2 < TPB) issue_tile(tile0 + k + 2, k & 1);
    }
}

extern "C" void kernel_launch(void* const* d_in, const int* in_sizes, int n_in,
                              void* d_out, int out_size, void* d_ws, size_t ws_size,
                              hipStream_t stream) {
    const float* pa = (const float*)d_in[0];   // (B, D, HIST)
    const float* w1 = (const float*)d_in[1];   // (M, H, D)
    const float* b1 = (const float*)d_in[2];   // (1, H, D)
    const float* b2 = (const float*)d_in[3];   // (1, H, D)
    const float* b3 = (const float*)d_in[4];   // (1, D)
    const float* cw = (const float*)d_in[5];   // (M,)
    const float* ss = (const float*)d_in[6];   // (RANK,)
    const float* sh = (const float*)d_in[7];   // (RANK,)
    const float* al = (const float*)d_in[8];   // (1,)
    const float* rs = (const float*)d_in[9];   // (1,)
    float* out = (float*)d_out;                // (B, D) f32

    fused_kernel<<<NBLOCKS, 256, 0, stream>>>(pa, w1, b1, b2, b3, cw, ss, sh, al, rs, out);
}

// Round 8
// 155.572 us; speedup vs baseline: 1.9698x; 1.9698x over previous
//
#include <hip/hip_runtime.h>
#include <math.h>

#define B_N    32768
#define D_N    128
#define HIST_N 30
#define M_N    15
#define H_N    4

#define TILE_ROWS   256
#define ROW_BYTES   (HIST_N * 4)                  // 120 B per input row
#define TILE_BYTES  (TILE_ROWS * ROW_BYTES)       // 30720 B of source per tile
// staged form: 16 floats per row (elems 14..29), 64 B -> tile = 16 KB
#define STG_ROW_F   16
#define STG_TILE_F  (TILE_ROWS * STG_ROW_F)       // 4096 floats = 16 KB
#define WAVE_ROWS   64                            // rows staged+computed per wave
#define NBLOCKS     1024                          // 4 resident blocks/CU target
#define TPB         (B_N * D_N / TILE_ROWS / NBLOCKS)   // 16 tiles per block
#define LOADS_PER_TILE 4                          // per-wave gload16 calls

__device__ __forceinline__ void gload16(const void* g, float* l) {
    __builtin_amdgcn_global_load_lds(
        (const __attribute__((address_space(1))) unsigned int*)g,
        (__attribute__((address_space(3))) unsigned int*)l, 16, 0, 0);
}

// ---------------------------------------------------------------------------
// Single fused persistent kernel.
// Param math (once, overlapped with the first two tiles' DMA): softmax ->
// W1c -> 4x4 Gram -> f32 Jacobi -> shared-eigenvector double spectral op
// (M2 = U diag(c1) U^T, M3 = U diag(c1*c2) U^T) -> per-thread w2v/w3v.
// Streaming: per-wave counted-vmcnt pipeline, no main-loop barriers.
// Stage only row tail (floats 14..29, 64 B, dword-aligned) with
// chunk-swizzled per-lane global addresses; LDS layout [g][chunk][row16]
// (g-group stride = 256 FLOATS — r7 bug was using the byte stride here).
// Each 16-lane quarter reads a contiguous 256 B span -> 2-way banks (free).
// ---------------------------------------------------------------------------
__global__ __launch_bounds__(256, 3) void fused_kernel(
        const float* __restrict__ pa,
        const float* __restrict__ w1,
        const float* __restrict__ b1,
        const float* __restrict__ b2,
        const float* __restrict__ b3,
        const float* __restrict__ cw,
        const float* __restrict__ ss,
        const float* __restrict__ sh,
        const float* __restrict__ al,
        const float* __restrict__ rs,
        float* __restrict__ out) {
    const int tid   = threadIdx.x;
    const int lane  = tid & 63;
    const int wv_id = tid >> 6;                 // wave 0..3
    const int row_w = lane;                     // row within wave's 64 rows
    const int d     = (wv_id * WAVE_ROWS + row_w) & (D_N - 1);

    __shared__ __align__(16) float lds[2][STG_TILE_F];    // 2 x 16 KB
    __shared__ float W1c[H_N][D_N];                       // 2 KB
    __shared__ float Gsh[16];
    __shared__ float Msh[32];                             // M2[16], M3[16]

    const char* pab = (const char*)pa;
    const size_t tile0 = (size_t)blockIdx.x * TPB;

    // stage this wave's 64 rows: 4 calls, each 16 rows x 4 chunks of 16B.
    // lane l -> row16 = l&15, chunk = l>>4 ; global: row*120 + 56 + chunk*16
    // LDS (linear, base+l*16): [g][chunk][row16][16B]
    auto issue_tile = [&](size_t t, int buf) {
        const char* gw = pab + t * TILE_BYTES + (size_t)wv_id * WAVE_ROWS * ROW_BYTES
                         + (size_t)(lane & 15) * ROW_BYTES + 56 + (lane >> 4) * 16;
        float* lw = &lds[buf][0] + wv_id * (WAVE_ROWS * STG_ROW_F);
#pragma unroll
        for (int g = 0; g < 4; ++g)
            gload16(gw + g * (16 * ROW_BYTES), lw + g * 256);
    };

    // prologue: two tiles in flight before anything else
    issue_tile(tile0, 0);
    issue_tile(tile0 + 1, 1);

    // ---- per-d parameter loads (regular VMEM, overlap the DMAs) ----
    float wv[M_N][H_N];
#pragma unroll
    for (int m = 0; m < M_N; ++m)
#pragma unroll
        for (int h = 0; h < H_N; ++h)
            wv[m][h] = w1[(m * H_N + h) * D_N + d];

    float b1v[H_N], b2v[H_N];
#pragma unroll
    for (int h = 0; h < H_N; ++h) {
        b1v[h] = b1[h * D_N + d];
        b2v[h] = b2[h * D_N + d];
    }
    const float b3v = b3[d];

    // ---- softmax(cw), redundant per-thread ----
    float swm[M_N];
    {
        float mx = cw[0];
#pragma unroll
        for (int m = 1; m < M_N; ++m) mx = fmaxf(mx, cw[m]);
        float s = 0.f;
#pragma unroll
        for (int m = 0; m < M_N; ++m) { swm[m] = expf(cw[m] - mx); s += swm[m]; }
        float inv = 1.f / s;
#pragma unroll
        for (int m = 0; m < M_N; ++m) swm[m] *= inv;
    }

    // ---- W1c into LDS ----
    if (tid < 128) {
#pragma unroll
        for (int h = 0; h < H_N; ++h) {
            float acc = 0.f;
#pragma unroll
            for (int m = 0; m < M_N; ++m)
                acc = fmaf(swm[m], w1[(m * H_N + h) * D_N + tid], acc);
            W1c[h][tid] = acc;
        }
    }
    asm volatile("s_waitcnt lgkmcnt(0)" ::: "memory");
    __builtin_amdgcn_s_barrier();

    // ---- Gram (16 threads, staggered) ----
    if (tid < 16) {
        const int i = tid >> 2, j = tid & 3;
        float s = 0.f;
        for (int st = 0; st < 128; ++st) {
            int dd = (st + tid * 8) & 127;
            s = fmaf(W1c[i][dd], W1c[j][dd], s);
        }
        Gsh[tid] = s;
    }
    asm volatile("s_waitcnt lgkmcnt(0)" ::: "memory");
    __builtin_amdgcn_s_barrier();

    // ---- thread 0: Jacobi + two-stage spectral scalars -> M2, M3 ----
    if (tid == 0) {
        float G[4][4], U[4][4];
#pragma unroll
        for (int i = 0; i < 4; ++i)
#pragma unroll
            for (int j = 0; j < 4; ++j) {
                G[i][j] = Gsh[i * 4 + j];
                U[i][j] = (i == j) ? 1.f : 0.f;
            }
        for (int sweep = 0; sweep < 6; ++sweep)
            for (int p = 0; p < 3; ++p)
                for (int q = p + 1; q < 4; ++q) {
                    float apq = G[p][q];
                    if (fabsf(apq) < 1e-30f) continue;
                    float theta = (G[q][q] - G[p][p]) / (2.f * apq);
                    float t = ((theta >= 0.f) ? 1.f : -1.f) /
                              (fabsf(theta) + sqrtf(theta * theta + 1.f));
                    float c = 1.f / sqrtf(t * t + 1.f), sn = t * c;
                    for (int i = 0; i < 4; ++i) {
                        float gip = G[i][p], giq = G[i][q];
                        G[i][p] = c * gip - sn * giq;
                        G[i][q] = sn * gip + c * giq;
                    }
                    for (int i = 0; i < 4; ++i) {
                        float gpi = G[p][i], gqi = G[q][i];
                        G[p][i] = c * gpi - sn * gqi;
                        G[q][i] = sn * gpi + c * gqi;
                    }
                    for (int i = 0; i < 4; ++i) {
                        float uip = U[i][p], uiq = U[i][q];
                        U[i][p] = c * uip - sn * uiq;
                        U[i][q] = sn * uip + c * uiq;
                    }
                }
        float lam[4];
#pragma unroll
        for (int i = 0; i < 4; ++i) lam[i] = G[i][i];
        int ord[4] = {0, 1, 2, 3};
        for (int i = 0; i < 4; ++i)
            for (int j = i + 1; j < 4; ++j)
                if (lam[ord[j]] > lam[ord[i]]) { int t2 = ord[i]; ord[i] = ord[j]; ord[j] = t2; }

        const float a = al[0], r = rs[0];
        float c1[4], S2a[4];
        for (int p = 0; p < 4; ++p) {
            int e = ord[p];
            float S = sqrtf(fmaxf(lam[e], 0.f));
            float x = ss[p];
            float sp = (x > 20.f) ? x : log1pf(expf(x));
            float ratio = (S > 1e-30f) ? ((sp * S + sh[p]) / S) : sp;
            c1[e] = a * ratio + r;
            S2a[e] = fabsf(c1[e]) * S;      // |singular values| of W2
        }
        int ord2[4] = {0, 1, 2, 3};
        for (int i = 0; i < 4; ++i)
            for (int j = i + 1; j < 4; ++j)
                if (S2a[ord2[j]] > S2a[ord2[i]]) { int t2 = ord2[i]; ord2[i] = ord2[j]; ord2[j] = t2; }
        float c12[4];
        for (int p = 0; p < 4; ++p) {
            int e = ord2[p];
            float Sa = S2a[e];
            float x = ss[p];
            float sp = (x > 20.f) ? x : log1pf(expf(x));
            float ratio2 = (Sa > 1e-30f) ? ((sp * Sa + sh[p]) / Sa) : sp;
            c12[e] = (a * ratio2 + r) * c1[e];
        }
#pragma unroll
        for (int i = 0; i < 4; ++i)
#pragma unroll
            for (int j = 0; j < 4; ++j) {
                float m2 = 0.f, m3 = 0.f;
#pragma unroll
                for (int e = 0; e < 4; ++e) {
                    float uu = U[i][e] * U[j][e];
                    m2 = fmaf(uu, c1[e], m2);
                    m3 = fmaf(uu, c12[e], m3);
                }
                Msh[i * 4 + j] = m2;
                Msh[16 + i * 4 + j] = m3;
            }
    }
    asm volatile("s_waitcnt lgkmcnt(0)" ::: "memory");
    __builtin_amdgcn_s_barrier();

    // ---- per-thread W2/W3 columns ----
    float w2v[H_N], w3v[H_N];
#pragma unroll
    for (int h = 0; h < H_N; ++h) {
        float s2 = 0.f, s3 = 0.f;
#pragma unroll
        for (int k4 = 0; k4 < 4; ++k4) {
            float wc = W1c[k4][d];
            s2 = fmaf(Msh[h * 4 + k4], wc, s2);
            s3 = fmaf(Msh[16 + h * 4 + k4], wc, s3);
        }
        w2v[h] = s2;
        w3v[h] = s3;
    }

    // thread's LDS read base (FLOAT units): [g=row_w>>4]*256 + chunk*64 + (row_w&15)*4
    const int rd_base = wv_id * (WAVE_ROWS * STG_ROW_F)
                      + (row_w >> 4) * 256 + (row_w & 15) * 4;

    // ---- main streaming loop: per-wave counted-vmcnt pipeline ----
    for (int k = 0; k < TPB; ++k) {
        if (k == TPB - 1)
            asm volatile("s_waitcnt vmcnt(0)" ::: "memory");
        else
            asm volatile("s_waitcnt vmcnt(4)" ::: "memory");   // = LOADS_PER_TILE

        const float* L = &lds[k & 1][0] + rd_base;
        // x4[c] = floats (14+4c .. 17+4c) of the row; x4[0].x (elem 14) unused
        float4 x4[4];
#pragma unroll
        for (int c = 0; c < 4; ++c)
            x4[c] = *(const float4*)(L + c * 64);   // 16B-aligned

        const float xe[16] = {x4[0].x, x4[0].y, x4[0].z, x4[0].w,
                              x4[1].x, x4[1].y, x4[1].z, x4[1].w,
                              x4[2].x, x4[2].y, x4[2].z, x4[2].w,
                              x4[3].x, x4[3].y, x4[3].z, x4[3].w};
        float h1[H_N] = {0.f, 0.f, 0.f, 0.f};
#pragma unroll
        for (int m = 0; m < M_N; ++m)
#pragma unroll
            for (int h = 0; h < H_N; ++h)
                h1[h] = fmaf(xe[1 + m], wv[m][h], h1[h]);

        float acc = b3v;
#pragma unroll
        for (int h = 0; h < H_N; ++h) {
            float v = fmaxf(h1[h] + b1v[h], 0.f);
            float u = fmaxf(fmaf(v, w2v[h], b2v[h]), 0.f);
            acc = fmaf(u, w3v[h], acc);
        }
        out[(tile0 + k) * TILE_ROWS + wv_id * WAVE_ROWS + row_w] = acc;

        asm volatile("" ::: "memory");   // pin reads/store before next DMA issue
        if (k + 2 < TPB) issue_tile(tile0 + k + 2, k & 1);
    }
}

extern "C" void kernel_launch(void* const* d_in, const int* in_sizes, int n_in,
                              void* d_out, int out_size, void* d_ws, size_t ws_size,
                              hipStream_t stream) {
    const float* pa = (const float*)d_in[0];   // (B, D, HIST)
    const float* w1 = (const float*)d_in[1];   // (M, H, D)
    const float* b1 = (const float*)d_in[2];   // (1, H, D)
    const float* b2 = (const float*)d_in[3];   // (1, H, D)
    const float* b3 = (const float*)d_in[4];   // (1, D)
    const float* cw = (const float*)d_in[5];   // (M,)
    const float* ss = (const float*)d_in[6];   // (RANK,)
    const float* sh = (const float*)d_in[7];   // (RANK,)
    const float* al = (const float*)d_in[8];   // (1,)
    const float* rs = (const float*)d_in[9];   // (1,)
    float* out = (float*)d_out;                // (B, D) f32

    fused_kernel<<<NBLOCKS, 256, 0, stream>>>(pa, w1, b1, b2, b3, cw, ss, sh, al, rs, out);
}

// Round 9
// 139.443 us; speedup vs baseline: 2.1977x; 1.1157x over previous
//
#include <hip/hip_runtime.h>
#include <math.h>

#define B_N    32768
#define D_N    128
#define HIST_N 30
#define M_N    15
#define H_N    4

#define TILE_ROWS   128
#define ROW_BYTES   (HIST_N * 4)                  // 120 B
#define TILE_FLOATS (TILE_ROWS * HIST_N)          // 3840 floats = 15360 B
#define TILE_BYTES  (TILE_FLOATS * 4)
#define WAVE_ROWS   32                            // rows per wave
#define WAVE_FLOATS (WAVE_ROWS * HIST_N)          // 960 floats = 3840 B
#define WAVE_BYTES  (WAVE_FLOATS * 4)
#define NT_TILES    (B_N * D_N / TILE_ROWS)       // 32768 tiles
#define NBLOCKS     768                           // 3/CU — single generation
#define LOADS_PER_TILE 6                          // 3 x gload16 + 3 x gload4

__device__ __forceinline__ void gload16(const void* g, float* l) {
    __builtin_amdgcn_global_load_lds(
        (const __attribute__((address_space(1))) unsigned int*)g,
        (__attribute__((address_space(3))) unsigned int*)l, 16, 0, 0);
}
__device__ __forceinline__ void gload4(const void* g, float* l) {
    __builtin_amdgcn_global_load_lds(
        (const __attribute__((address_space(1))) unsigned int*)g,
        (__attribute__((address_space(3))) unsigned int*)l, 4, 0, 0);
}

// ---------------------------------------------------------------------------
// Fused persistent kernel. Param math (overlapped with first tiles' DMA):
// softmax -> W1c -> 4x4 Gram -> f32 Jacobi -> shared-eigenvector double
// spectral op (M2 = U diag(c1) U^T, M3 = U diag(c1*c2) U^T) -> w2v/w3v regs.
// Streaming: DENSE whole-row DMA staging (every instruction covers one
// contiguous span: 3x1024B + 3x256B per wave per 128-row tile), wave-private
// counted-vmcnt double-buffer, no main-loop barriers, grid-stride tiles.
// r9 vs r6: launch_bounds (256,3) not (256,4) — (256,4) spilled (VGPR=64,
// 46MB scratch writes, 306us). r9 vs r8: dense staging, not row-tail scatter
// (64 scattered 16B chunks/instr quadrupled L2 request rate, 155us).
// ---------------------------------------------------------------------------
__global__ __launch_bounds__(256, 3) void fused_kernel(
        const float* __restrict__ pa,
        const float* __restrict__ w1,
        const float* __restrict__ b1,
        const float* __restrict__ b2,
        const float* __restrict__ b3,
        const float* __restrict__ cw,
        const float* __restrict__ ss,
        const float* __restrict__ sh,
        const float* __restrict__ al,
        const float* __restrict__ rs,
        float* __restrict__ out) {
    const int tid   = threadIdx.x;
    const int lane  = tid & 63;
    const int wv_id = tid >> 6;                 // wave 0..3
    const int row_w = lane & (WAVE_ROWS - 1);   // row within wave (lanes<32 compute)
    const int d     = wv_id * WAVE_ROWS + row_w;   // 0..127

    __shared__ __align__(16) float lds[2][TILE_FLOATS];   // 2 x 15360 B
    __shared__ float W1c[H_N][D_N];                       // 2 KB
    __shared__ float Gsh[16];
    __shared__ float Msh[32];                             // M2[16], M3[16]

    const char* pab = (const char*)pa;
    const int bid = blockIdx.x;
    const int nt = (NT_TILES - bid + NBLOCKS - 1) / NBLOCKS;   // 42 or 43

    // dense staging: wave stages its own 32 rows (3840 B contiguous)
    auto issue_tile = [&](size_t t, int buf) {
        const char* gw = pab + t * TILE_BYTES + (size_t)wv_id * WAVE_BYTES;
        float* lw = &lds[buf][0] + wv_id * WAVE_FLOATS;
#pragma unroll
        for (int c = 0; c < 3; ++c)
            gload16(gw + c * 1024 + lane * 16, lw + c * 256);
#pragma unroll
        for (int c = 0; c < 3; ++c)
            gload4(gw + 3072 + c * 256 + lane * 4, lw + 768 + c * 64);
    };
    auto tile_of = [&](int k) { return (size_t)bid + (size_t)k * NBLOCKS; };

    // prologue: two tiles in flight before anything else (nt >= 42 always)
    issue_tile(tile_of(0), 0);
    issue_tile(tile_of(1), 1);

    // ---- per-d parameter loads (regular VMEM, overlap the DMAs) ----
    float wv[M_N][H_N];
#pragma unroll
    for (int m = 0; m < M_N; ++m)
#pragma unroll
        for (int h = 0; h < H_N; ++h)
            wv[m][h] = w1[(m * H_N + h) * D_N + d];

    float b1v[H_N], b2v[H_N];
#pragma unroll
    for (int h = 0; h < H_N; ++h) {
        b1v[h] = b1[h * D_N + d];
        b2v[h] = b2[h * D_N + d];
    }
    const float b3v = b3[d];

    // ---- softmax(cw), redundant per-thread ----
    float swm[M_N];
    {
        float mx = cw[0];
#pragma unroll
        for (int m = 1; m < M_N; ++m) mx = fmaxf(mx, cw[m]);
        float s = 0.f;
#pragma unroll
        for (int m = 0; m < M_N; ++m) { swm[m] = expf(cw[m] - mx); s += swm[m]; }
        float inv = 1.f / s;
#pragma unroll
        for (int m = 0; m < M_N; ++m) swm[m] *= inv;
    }

    // ---- W1c into LDS ----
    if (tid < 128) {
#pragma unroll
        for (int h = 0; h < H_N; ++h) {
            float acc = 0.f;
#pragma unroll
            for (int m = 0; m < M_N; ++m)
                acc = fmaf(swm[m], w1[(m * H_N + h) * D_N + tid], acc);
            W1c[h][tid] = acc;
        }
    }
    asm volatile("s_waitcnt lgkmcnt(0)" ::: "memory");
    __builtin_amdgcn_s_barrier();

    // ---- Gram (16 threads, staggered) ----
    if (tid < 16) {
        const int i = tid >> 2, j = tid & 3;
        float s = 0.f;
        for (int st = 0; st < 128; ++st) {
            int dd = (st + tid * 8) & 127;
            s = fmaf(W1c[i][dd], W1c[j][dd], s);
        }
        Gsh[tid] = s;
    }
    asm volatile("s_waitcnt lgkmcnt(0)" ::: "memory");
    __builtin_amdgcn_s_barrier();

    // ---- thread 0: Jacobi + two-stage spectral scalars -> M2, M3 ----
    if (tid == 0) {
        float G[4][4], U[4][4];
#pragma unroll
        for (int i = 0; i < 4; ++i)
#pragma unroll
            for (int j = 0; j < 4; ++j) {
                G[i][j] = Gsh[i * 4 + j];
                U[i][j] = (i == j) ? 1.f : 0.f;
            }
        for (int sweep = 0; sweep < 6; ++sweep)
            for (int p = 0; p < 3; ++p)
                for (int q = p + 1; q < 4; ++q) {
                    float apq = G[p][q];
                    if (fabsf(apq) < 1e-30f) continue;
                    float theta = (G[q][q] - G[p][p]) / (2.f * apq);
                    float t = ((theta >= 0.f) ? 1.f : -1.f) /
                              (fabsf(theta) + sqrtf(theta * theta + 1.f));
                    float c = 1.f / sqrtf(t * t + 1.f), sn = t * c;
                    for (int i = 0; i < 4; ++i) {
                        float gip = G[i][p], giq = G[i][q];
                        G[i][p] = c * gip - sn * giq;
                        G[i][q] = sn * gip + c * giq;
                    }
                    for (int i = 0; i < 4; ++i) {
                        float gpi = G[p][i], gqi = G[q][i];
                        G[p][i] = c * gpi - sn * gqi;
                        G[q][i] = sn * gpi + c * gqi;
                    }
                    for (int i = 0; i < 4; ++i) {
                        float uip = U[i][p], uiq = U[i][q];
                        U[i][p] = c * uip - sn * uiq;
                        U[i][q] = sn * uip + c * uiq;
                    }
                }
        float lam[4];
#pragma unroll
        for (int i = 0; i < 4; ++i) lam[i] = G[i][i];
        int ord[4] = {0, 1, 2, 3};
        for (int i = 0; i < 4; ++i)
            for (int j = i + 1; j < 4; ++j)
                if (lam[ord[j]] > lam[ord[i]]) { int t2 = ord[i]; ord[i] = ord[j]; ord[j] = t2; }

        const float a = al[0], r = rs[0];
        float c1[4], S2a[4];
        for (int p = 0; p < 4; ++p) {
            int e = ord[p];
            float S = sqrtf(fmaxf(lam[e], 0.f));
            float x = ss[p];
            float sp = (x > 20.f) ? x : log1pf(expf(x));
            float ratio = (S > 1e-30f) ? ((sp * S + sh[p]) / S) : sp;
            c1[e] = a * ratio + r;
            S2a[e] = fabsf(c1[e]) * S;      // |singular values| of W2
        }
        int ord2[4] = {0, 1, 2, 3};
        for (int i = 0; i < 4; ++i)
            for (int j = i + 1; j < 4; ++j)
                if (S2a[ord2[j]] > S2a[ord2[i]]) { int t2 = ord2[i]; ord2[i] = ord2[j]; ord2[j] = t2; }
        float c12[4];
        for (int p = 0; p < 4; ++p) {
            int e = ord2[p];
            float Sa = S2a[e];
            float x = ss[p];
            float sp = (x > 20.f) ? x : log1pf(expf(x));
            float ratio2 = (Sa > 1e-30f) ? ((sp * Sa + sh[p]) / Sa) : sp;
            c12[e] = (a * ratio2 + r) * c1[e];
        }
#pragma unroll
        for (int i = 0; i < 4; ++i)
#pragma unroll
            for (int j = 0; j < 4; ++j) {
                float m2 = 0.f, m3 = 0.f;
#pragma unroll
                for (int e = 0; e < 4; ++e) {
                    float uu = U[i][e] * U[j][e];
                    m2 = fmaf(uu, c1[e], m2);
                    m3 = fmaf(uu, c12[e], m3);
                }
                Msh[i * 4 + j] = m2;
                Msh[16 + i * 4 + j] = m3;
            }
    }
    asm volatile("s_waitcnt lgkmcnt(0)" ::: "memory");
    __builtin_amdgcn_s_barrier();

    // ---- per-thread W2/W3 columns ----
    float w2v[H_N], w3v[H_N];
#pragma unroll
    for (int h = 0; h < H_N; ++h) {
        float s2 = 0.f, s3 = 0.f;
#pragma unroll
        for (int k4 = 0; k4 < 4; ++k4) {
            float wc = W1c[k4][d];
            s2 = fmaf(Msh[h * 4 + k4], wc, s2);
            s3 = fmaf(Msh[16 + h * 4 + k4], wc, s3);
        }
        w2v[h] = s2;
        w3v[h] = s3;
    }

    const bool active = (lane < WAVE_ROWS);
    // thread's LDS row base (floats, relative to buffer): wave region + row*30
    const int rd_base = wv_id * WAVE_FLOATS + row_w * HIST_N + (HIST_N - M_N);

    // ---- main streaming loop: per-wave counted-vmcnt pipeline ----
    for (int k = 0; k < nt; ++k) {
        if (k == nt - 1)
            asm volatile("s_waitcnt vmcnt(0)" ::: "memory");
        else
            asm volatile("s_waitcnt vmcnt(6)" ::: "memory");   // = LOADS_PER_TILE

        if (active) {
            const float* L = &lds[k & 1][0] + rd_base;
            float x0 = L[0];
            float h1[H_N];
#pragma unroll
            for (int h = 0; h < H_N; ++h) h1[h] = x0 * wv[0][h];
#pragma unroll
            for (int c = 0; c < 7; ++c) {
                float2 q = *(const float2*)(L + 1 + 2 * c);   // 8B-aligned
#pragma unroll
                for (int h = 0; h < H_N; ++h) h1[h] = fmaf(q.x, wv[1 + 2 * c][h], h1[h]);
#pragma unroll
                for (int h = 0; h < H_N; ++h) h1[h] = fmaf(q.y, wv[2 + 2 * c][h], h1[h]);
            }
            float acc = b3v;
#pragma unroll
            for (int h = 0; h < H_N; ++h) {
                float v = fmaxf(h1[h] + b1v[h], 0.f);
                float u = fmaxf(fmaf(v, w2v[h], b2v[h]), 0.f);
                acc = fmaf(u, w3v[h], acc);
            }
            out[tile_of(k) * TILE_ROWS + wv_id * WAVE_ROWS + row_w] = acc;
        }

        asm volatile("" ::: "memory");   // pin reads/store before next DMA issue
        if (k + 2 < nt) issue_tile(tile_of(k + 2), k & 1);
    }
}

extern "C" void kernel_launch(void* const* d_in, const int* in_sizes, int n_in,
                              void* d_out, int out_size, void* d_ws, size_t ws_size,
                              hipStream_t stream) {
    const float* pa = (const float*)d_in[0];   // (B, D, HIST)
    const float* w1 = (const float*)d_in[1];   // (M, H, D)
    const float* b1 = (const float*)d_in[2];   // (1, H, D)
    const float* b2 = (const float*)d_in[3];   // (1, H, D)
    const float* b3 = (const float*)d_in[4];   // (1, D)
    const float* cw = (const float*)d_in[5];   // (M,)
    const float* ss = (const float*)d_in[6];   // (RANK,)
    const float* sh = (const float*)d_in[7];   // (RANK,)
    const float* al = (const float*)d_in[8];   // (1,)
    const float* rs = (const float*)d_in[9];   // (1,)
    float* out = (float*)d_out;                // (B, D) f32

    fused_kernel<<<NBLOCKS, 256, 0, stream>>>(pa, w1, b1, b2, b3, cw, ss, sh, al, rs, out);
}